// Round 9
// baseline (171.642 us; speedup 1.0000x reference)
//
#include <hip/hip_runtime.h>
#include <hip/hip_bf16.h>
#include <math.h>

#define BATCH 16
#define SEQ 4096
#define HDIM 64

typedef __attribute__((ext_vector_type(8))) short bf16x8;   // 8 bf16 = 4 VGPR
typedef __attribute__((ext_vector_type(4))) float f32x4;
typedef __attribute__((ext_vector_type(8))) unsigned short us8;

// softmax scale (1/8) * log2(e) folded into Wq -> softmax in exp2 space.
// No running max: |s| < ~25 worst case => exp2/f32 sums can't overflow.
#define QSCALE 0.1803368801111601f

static __device__ __forceinline__ float exp2_fast(float x) {
#if __has_builtin(__builtin_amdgcn_exp2f)
    return __builtin_amdgcn_exp2f(x);
#else
    float r; asm("v_exp_f32 %0, %1" : "=v"(r) : "v"(x)); return r;
#endif
}

// async global->LDS, 16B/lane. LDS dest = wave-uniform base + lane*16 (m104).
static __device__ __forceinline__ void load_lds16(const void* g, void* l) {
    __builtin_amdgcn_global_load_lds(
        (const __attribute__((address_space(1))) unsigned int*)g,
        (__attribute__((address_space(3))) unsigned int*)l,
        16, 0, 0);
}

static __device__ __forceinline__ unsigned short bf16bits(float f) {
    __hip_bfloat16 h = __float2bfloat16(f);
    return *(unsigned short*)&h;
}

// ---------------- QKV projection ----------------
// As round 8, minus the x LDS staging: A-frags come straight from global x
// (tile is L1/L2-hot; removes 4 staging writes + 16 f32x4 LDS reads + one
// barrier per block). swt fill / B-frags / sout store path unchanged.
__global__ __launch_bounds__(256)
void qkv_mfma_kernel(const float* __restrict__ x,
                     const float* __restrict__ Wq,
                     const float* __restrict__ Wk,
                     const float* __restrict__ Wv,
                     __hip_bfloat16* __restrict__ qb,
                     __hip_bfloat16* __restrict__ kb,
                     __hip_bfloat16* __restrict__ vt) {
    __shared__ __attribute__((aligned(16))) __hip_bfloat16 swt[3 * 64 * 64];   // 24 KB
    __shared__ __attribute__((aligned(16))) __hip_bfloat16 sout[64][80];       // 10.2 KB
    const int tid = threadIdx.x;
    const int wv = tid >> 6;
    const int lane = tid & 63;
    const int quad = lane >> 4;
    const int ml = lane & 15;
    const size_t row0 = (size_t)blockIdx.x * 64;
    const int batch = (int)(row0 >> 12);
    const int t0 = (int)(row0 & 4095);

    // W -> swt (XOR-swizzled [mat][n][k]); coalesced W reads.
    #pragma unroll
    for (int mat = 0; mat < 3; ++mat) {
        const float* W = (mat == 0) ? Wq : (mat == 1) ? Wk : Wv;
        const float sc = (mat == 0) ? QSCALE : 1.0f;
        const int n = tid & 63;
        #pragma unroll
        for (int i = 0; i < 16; ++i) {
            const int f = i * 256 + tid;
            const int k = f >> 6;
            swt[mat * 4096 + n * 64 + (((k >> 3) ^ (n & 7)) << 3) + (k & 7)] =
                __float2bfloat16(W[f] * sc);
        }
    }

    // A-frags directly from global x (rows wv*16+ml)
    bf16x8 a0, a1;
    {
        const float4* xr = (const float4*)(x + (row0 + wv * 16 + ml) * HDIM);
        float4 lo = xr[quad * 2], hi = xr[quad * 2 + 1];
        float t8[8] = {lo.x, lo.y, lo.z, lo.w, hi.x, hi.y, hi.z, hi.w};
        #pragma unroll
        for (int j = 0; j < 8; ++j) a0[j] = (short)bf16bits(t8[j]);
        lo = xr[8 + quad * 2]; hi = xr[9 + quad * 2];
        float u8[8] = {lo.x, lo.y, lo.z, lo.w, hi.x, hi.y, hi.z, hi.w};
        #pragma unroll
        for (int j = 0; j < 8; ++j) a1[j] = (short)bf16bits(u8[j]);
    }
    __syncthreads();   // swt ready

    #pragma unroll
    for (int mat = 0; mat < 3; ++mat) {
        const __hip_bfloat16* wb = swt + mat * 4096;
        f32x4 acc[4];
        #pragma unroll
        for (int nt = 0; nt < 4; ++nt) {
            const int n = nt * 16 + ml;
            const int nx = n & 7;
            const bf16x8 bl = *(const bf16x8*)(wb + (size_t)n * 64 + (size_t)((quad) ^ nx) * 8);
            const bf16x8 bh = *(const bf16x8*)(wb + (size_t)n * 64 + (size_t)((quad + 4) ^ nx) * 8);
            acc[nt] = __builtin_amdgcn_mfma_f32_16x16x32_bf16(a0, bl, (f32x4){0.f,0.f,0.f,0.f}, 0, 0, 0);
            acc[nt] = __builtin_amdgcn_mfma_f32_16x16x32_bf16(a1, bh, acc[nt], 0, 0, 0);
        }

        if (mat < 2) {
            #pragma unroll
            for (int nt = 0; nt < 4; ++nt)
                #pragma unroll
                for (int r = 0; r < 4; ++r)
                    sout[wv * 16 + quad * 4 + r][nt * 16 + ml] = __float2bfloat16(acc[nt][r]);
        } else {
            #pragma unroll
            for (int nt = 0; nt < 4; ++nt)
                #pragma unroll
                for (int r = 0; r < 4; ++r)
                    sout[nt * 16 + ml][wv * 16 + quad * 4 + r] = __float2bfloat16(acc[nt][r]);
        }
        __syncthreads();
        __hip_bfloat16* dst = (mat == 0) ? qb : (mat == 1) ? kb : vt;
        #pragma unroll
        for (int c2 = 0; c2 < 2; ++c2) {
            const int cc = c2 * 256 + tid;
            const int row = cc >> 3, g = cc & 7;
            us8 u = *(const us8*)&sout[row][g * 8];
            if (mat < 2)
                *(us8*)(dst + (row0 + row) * HDIM + g * 8) = u;
            else
                *(us8*)(dst + ((size_t)batch * HDIM + row) * SEQ + t0 + g * 8) = u;
        }
        __syncthreads();
    }
}

// ---------------- MFMA flash attention, 32 q-rows per wave ----------------
// Rounds 4-8 were LDS-pipe-bound (~270 LDS cyc/wave-tile, 70% busy): K/V
// frag reads are per-wave re-reads of the shared tile. Wave now owns TWO
// stacked 16-row m-tiles sharing the same K/V frags -> wave-tile count
// halves, K/V read cost amortized 2x. Block = 4 waves x 32 rows = 128 q-rows;
// grid 512 (2 blocks/CU), qt paired {31-mid, mid} -> 68 tile-steps per CU.
__global__ __launch_bounds__(256, 2)
void flash_mfma_kernel(const __hip_bfloat16* __restrict__ qb,
                       const __hip_bfloat16* __restrict__ kbuf,
                       const __hip_bfloat16* __restrict__ vt,
                       float* __restrict__ out) {
    __shared__ __attribute__((aligned(16))) __hip_bfloat16 sk[64 * 64];
    __shared__ __attribute__((aligned(16))) __hip_bfloat16 sv[64 * 64];
    __shared__ __attribute__((aligned(16))) __hip_bfloat16 pb[4][32][72];
    const int tid = threadIdx.x;
    const int wv = tid >> 6;
    const int lane = tid & 63;
    const int quad = lane >> 4;
    const int ml = lane & 15;

    const int id = blockIdx.x;
    const int b = id & 15;                 // id%8 pins batch->XCD
    const int t = id >> 4;                 // [0,32)
    const int qt = (t >> 4) ? (t & 15) : (31 - (t & 15));  // paired: const work/CU
    const int qbw = qt * 128 + wv * 32;    // wave's first q row
    const size_t bb = (size_t)b * SEQ * HDIM;

    const __hip_bfloat16* Q = qb + bb;
    const __hip_bfloat16* K = kbuf + bb;
    const __hip_bfloat16* VT = vt + bb;    // [b][64][SEQ]

    // Q A-frags: 2 m-tiles x 2 k-halves
    bf16x8 a[2][2];
    #pragma unroll
    for (int mt = 0; mt < 2; ++mt)
        #pragma unroll
        for (int h = 0; h < 2; ++h)
            a[mt][h] = *(const bf16x8*)(Q + (size_t)(qbw + mt * 16 + ml) * HDIM + h * 32 + quad * 8);

    bf16x8 ones;
    #pragma unroll
    for (int j = 0; j < 8; ++j) ones[j] = (short)0x3F80;

    f32x4 acc[2][4];
    #pragma unroll
    for (int mt = 0; mt < 2; ++mt)
        #pragma unroll
        for (int nt = 0; nt < 4; ++nt) acc[mt][nt] = (f32x4){0.f, 0.f, 0.f, 0.f};
    f32x4 lacc[2] = {(f32x4){0.f,0.f,0.f,0.f}, (f32x4){0.f,0.f,0.f,0.f}};

    // staging geometry: 2 rounds x 64 lanes per wave, XOR chunk swizzle
    const int s0 = wv * 128 + lane;
    const int s1 = s0 + 64;
    const int r0row = s0 >> 3, r0ch = (s0 & 7) ^ (r0row & 7);
    const int r1row = s1 >> 3, r1ch = (s1 & 7) ^ (r1row & 7);
    __hip_bfloat16* ldsb0k = sk + (size_t)(wv * 128) * 8;
    __hip_bfloat16* ldsb1k = sk + (size_t)(wv * 128 + 64) * 8;
    __hip_bfloat16* ldsb0v = sv + (size_t)(wv * 128) * 8;
    __hip_bfloat16* ldsb1v = sv + (size_t)(wv * 128 + 64) * 8;

    const int ntiles = 2 * qt + 2;   // uniform per block (waves 0/1 waste one masked tile)
    for (int tile = 0; tile < ntiles; ++tile) {
        const int kb0 = tile * 64;
        __syncthreads();
        load_lds16(K + (size_t)(kb0 + r0row) * HDIM + r0ch * 8, ldsb0k);
        load_lds16(K + (size_t)(kb0 + r1row) * HDIM + r1ch * 8, ldsb1k);
        load_lds16(VT + (size_t)r0row * SEQ + kb0 + r0ch * 8, ldsb0v);
        load_lds16(VT + (size_t)r1row * SEQ + kb0 + r1ch * 8, ldsb1v);
        asm volatile("s_waitcnt vmcnt(0)" ::: "memory");
        __syncthreads();

        // --- S = Q K^T: K frags shared by both m-tiles ---
        f32x4 s[2][4];
        #pragma unroll
        for (int tt = 0; tt < 4; ++tt) {
            const int row = tt * 16 + ml;
            const int rb = row << 3, rx = row & 7;
            const bf16x8 kl = *(const bf16x8*)(sk + (size_t)((rb | (quad ^ rx)) * 8));
            const bf16x8 kh = *(const bf16x8*)(sk + (size_t)((rb | ((quad + 4) ^ rx)) * 8));
            #pragma unroll
            for (int mt = 0; mt < 2; ++mt) {
                s[mt][tt] = __builtin_amdgcn_mfma_f32_16x16x32_bf16(a[mt][0], kl, (f32x4){0.f,0.f,0.f,0.f}, 0, 0, 0);
                s[mt][tt] = __builtin_amdgcn_mfma_f32_16x16x32_bf16(a[mt][1], kh, s[mt][tt], 0, 0, 0);
            }
        }

        // --- p = exp2(s), causal zero when tile can cross the diagonal ---
        const bool edge = (kb0 + 64 > qbw);
        #pragma unroll
        for (int mt = 0; mt < 2; ++mt)
            #pragma unroll
            for (int tt = 0; tt < 4; ++tt) {
                const int key = kb0 + tt * 16 + ml;
                #pragma unroll
                for (int r = 0; r < 4; ++r) {
                    float pv = exp2_fast(s[mt][tt][r]);
                    if (edge && (key > qbw + mt * 16 + quad * 4 + r)) pv = 0.f;
                    pb[wv][mt * 16 + quad * 4 + r][tt * 16 + ml] = __float2bfloat16(pv);
                }
            }
        asm volatile("s_waitcnt lgkmcnt(0)" ::: "memory");

        // --- V frags once, shared by both m-tiles ---
        bf16x8 vfl[4], vfh[4];
        #pragma unroll
        for (int nt = 0; nt < 4; ++nt) {
            const int row = nt * 16 + ml;
            const int rb = row << 3, rx = row & 7;
            vfl[nt] = *(const bf16x8*)(sv + (size_t)((rb | (quad ^ rx)) * 8));
            vfh[nt] = *(const bf16x8*)(sv + (size_t)((rb | ((quad + 4) ^ rx)) * 8));
        }

        #pragma unroll
        for (int mt = 0; mt < 2; ++mt) {
            const bf16x8 ap0 = *(const bf16x8*)&pb[wv][mt * 16 + ml][quad * 8];
            const bf16x8 ap1 = *(const bf16x8*)&pb[wv][mt * 16 + ml][32 + quad * 8];
            lacc[mt] = __builtin_amdgcn_mfma_f32_16x16x32_bf16(ap0, ones, lacc[mt], 0, 0, 0);
            lacc[mt] = __builtin_amdgcn_mfma_f32_16x16x32_bf16(ap1, ones, lacc[mt], 0, 0, 0);
            #pragma unroll
            for (int nt = 0; nt < 4; ++nt) {
                acc[mt][nt] = __builtin_amdgcn_mfma_f32_16x16x32_bf16(ap0, vfl[nt], acc[mt][nt], 0, 0, 0);
                acc[mt][nt] = __builtin_amdgcn_mfma_f32_16x16x32_bf16(ap1, vfh[nt], acc[mt][nt], 0, 0, 0);
            }
        }
    }

    // epilogue: out[row][nt*16+ml] = acc/l
    #pragma unroll
    for (int mt = 0; mt < 2; ++mt)
        #pragma unroll
        for (int r = 0; r < 4; ++r) {
            const float inv = 1.0f / lacc[mt][r];
            const int row = qbw + mt * 16 + quad * 4 + r;
            float* orow = out + bb + (size_t)row * HDIM + ml;
            orow[0]  = acc[mt][0][r] * inv;
            orow[16] = acc[mt][1][r] * inv;
            orow[32] = acc[mt][2][r] * inv;
            orow[48] = acc[mt][3][r] * inv;
        }
}

extern "C" void kernel_launch(void* const* d_in, const int* in_sizes, int n_in,
                              void* d_out, int out_size, void* d_ws, size_t ws_size,
                              hipStream_t stream) {
    const float* x  = (const float*)d_in[0];
    const float* Wq = (const float*)d_in[1];
    const float* Wk = (const float*)d_in[2];
    const float* Wv = (const float*)d_in[3];
    float* outp = (float*)d_out;

    const size_t elems = (size_t)BATCH * SEQ * HDIM;
    __hip_bfloat16* qb = (__hip_bfloat16*)d_ws;           // 8 MB
    __hip_bfloat16* kb = qb + elems;                      // 8 MB
    __hip_bfloat16* vt = kb + elems;                      // 8 MB, [b][d][t]

    qkv_mfma_kernel<<<dim3(BATCH * SEQ / 64), 256, 0, stream>>>(x, Wq, Wk, Wv, qb, kb, vt);
    flash_mfma_kernel<<<dim3(BATCH * SEQ / 128), 256, 0, stream>>>(qb, kb, vt, outp);
}